// Round 3
// baseline (277.129 us; speedup 1.0000x reference)
//
#include <hip/hip_runtime.h>

// RandomShift: out[row, t] = x[row, t - s] if 0 <= t-s < T else 0
// x: [256, 160000] float32, shifts: [256] int32; s = shifts[row] - 16000 (row-uniform).
//
// Memory-bound shifted copy (163.84 MB in + 163.84 MB out), ~52us traffic floor.
// V4: aligned-load realignment. V1 (4 scalar loads/thread) was VMEM-issue-bound:
// 51M VMEM instrs / 256 CU ~ 84us of issue. V3's unaligned dwordx4 straddles a
// 64B line 25% of the time (split+replay). Here: loads are ALIGNED float4s
// covering x[a..a+7] (overlap between lanes = L1 hit, no extra HBM traffic);
// realignment r = a&3 is wave-uniform (s row-uniform) -> uniform 4-way branch,
// element shuffle in registers; two aligned float4 stores. <=5 VMEM per 8
// outputs -> ~100K VMEM/CU ~ 42us issue, below the BW floor. Zero-region
// threads store zeros with no loads. Boundary straddle (<=3 threads/row) scalar.

constexpr int T_LEN     = 160000;
constexpr int MAX_SHIFT = 16000;   // int(T * 0.1)
constexpr int ROWS      = 32 * 8;  // B * M
constexpr int VEC       = 8;       // floats per thread; T_LEN % VEC == 0

__global__ __launch_bounds__(256) void RandomShift_33079838113837_kernel(
    const float* __restrict__ x,
    const int*   __restrict__ shifts,
    float*       __restrict__ out) {
    const int row = blockIdx.y;                    // 0..ROWS-1, wave-uniform
    const int s   = shifts[row] - MAX_SHIFT;       // row-uniform shift

    const float* __restrict__ xr   = x   + (size_t)row * T_LEN;
    float*       __restrict__ outr = out + (size_t)row * T_LEN;

    const int t0 = (blockIdx.x * blockDim.x + threadIdx.x) * VEC;
    if (t0 >= T_LEN) return;                       // T_LEN % VEC == 0, no partial vec

    const int a = t0 - s;                          // source start for this thread

    float4* __restrict__ o0 = reinterpret_cast<float4*>(outr + t0);     // 32B-aligned
    float4* __restrict__ o1 = reinterpret_cast<float4*>(outr + t0 + 4);

    if (a >= 0 && a + 12 <= T_LEN) {
        // interior: aligned float4 granules; r wave-uniform
        const float4* __restrict__ p = reinterpret_cast<const float4*>(xr) + (a >> 2);
        const int r = a & 3;
        float4 A, B, C;
        if (r == 0) {
            A = p[0]; B = p[1];
            *o0 = A;
            *o1 = B;
        } else if (r == 1) {
            A = p[0]; B = p[1]; C = p[2];
            *o0 = make_float4(A.y, A.z, A.w, B.x);
            *o1 = make_float4(B.y, B.z, B.w, C.x);
        } else if (r == 2) {
            A = p[0]; B = p[1]; C = p[2];
            *o0 = make_float4(A.z, A.w, B.x, B.y);
            *o1 = make_float4(B.z, B.w, C.x, C.y);
        } else {
            A = p[0]; B = p[1]; C = p[2];
            *o0 = make_float4(A.w, B.x, B.y, B.z);
            *o1 = make_float4(B.w, C.x, C.y, C.z);
        }
    } else if (a + VEC <= 0 || a >= T_LEN) {
        // fully out of range: vectorized zero-fill, no loads
        const float4 z = make_float4(0.0f, 0.0f, 0.0f, 0.0f);
        *o0 = z;
        *o1 = z;
    } else {
        // boundary straddle (incl. right-edge r==0 corner): <=3 threads/row, scalar
#pragma unroll
        for (int j = 0; j < VEC; ++j) {
            const int src = a + j;
            outr[t0 + j] = (src >= 0 && src < T_LEN) ? xr[src] : 0.0f;
        }
    }
}

extern "C" void kernel_launch(void* const* d_in, const int* in_sizes, int n_in,
                              void* d_out, int out_size, void* d_ws, size_t ws_size,
                              hipStream_t stream) {
    const float* x      = (const float*)d_in[0];
    const int*   shifts = (const int*)d_in[1];
    float*       out    = (float*)d_out;

    const int vec_per_row = T_LEN / VEC;                   // 20000
    const int block = 256;
    dim3 grid((vec_per_row + block - 1) / block, ROWS, 1); // 79 x 256

    RandomShift_33079838113837_kernel<<<grid, block, 0, stream>>>(x, shifts, out);
}

// Round 4
// 269.535 us; speedup vs baseline: 1.0282x; 1.0282x over previous
//
#include <hip/hip_runtime.h>

// RandomShift: out[row, t] = x[row, t - s] if 0 <= t-s < T else 0
// x: [256, 160000] float32, shifts: [256] int32; s = shifts[row] - 16000 (row-uniform).
//
// V5 = V1 restored (empirical best, ~61us kernel dispatch, 86% of the 6.3 TB/s
// copy ceiling on 328 MB of traffic). Session evidence:
//   V2 (unaligned dwordx4 + nontemporal stores): 118us — NT stores caused 44%
//       HBM write amplification (WRITE 236MB vs 164MB) + ~2 TB/s write rate.
//   V3 (unaligned dwordx4): ~74us — 16B loads straddle a 64B line 25% of the
//       time (split+replay in TA).
//   V4 (aligned float4 + register realign): ~78us — 48B returned per 32B
//       produced (1.5x L1/TA data-return amplification) despite half the VMEM
//       instruction count of V1. VMEM issue rate is NOT the limiter.
// V1's pattern is the minimal-return-traffic realization: 4 predicated scalar
// loads (consecutive lanes at 16B stride fill every 64B line exactly once
// across the 4 instrs; OOB lanes exec-masked off) + one aligned float4 store.
// Remaining gap to the pure-copy floor (~52us) not reachable by instruction
// restructuring per V2-V4; the other ~200us of dur_us is two 640MB harness
// poison fills.

constexpr int T_LEN     = 160000;
constexpr int MAX_SHIFT = 16000;   // int(T * 0.1)
constexpr int ROWS      = 32 * 8;  // B * M

__global__ __launch_bounds__(256) void RandomShift_33079838113837_kernel(
    const float* __restrict__ x,
    const int*   __restrict__ shifts,
    float*       __restrict__ out) {
    const int row = blockIdx.y;                    // 0..ROWS-1, wave-uniform
    const int s   = shifts[row] - MAX_SHIFT;       // row-uniform shift

    const float* __restrict__ xr   = x   + (size_t)row * T_LEN;
    float*       __restrict__ outr = out + (size_t)row * T_LEN;

    const int t0 = (blockIdx.x * blockDim.x + threadIdx.x) * 4;
    if (t0 >= T_LEN) return;                       // T_LEN % 4 == 0, no partial vec

    const int src0 = t0 - s;

    float r[4];
#pragma unroll
    for (int j = 0; j < 4; ++j) {
        const int src = src0 + j;
        r[j] = (src >= 0 && src < T_LEN) ? xr[src] : 0.0f;
    }

    *reinterpret_cast<float4*>(outr + t0) = make_float4(r[0], r[1], r[2], r[3]);
}

extern "C" void kernel_launch(void* const* d_in, const int* in_sizes, int n_in,
                              void* d_out, int out_size, void* d_ws, size_t ws_size,
                              hipStream_t stream) {
    const float* x      = (const float*)d_in[0];
    const int*   shifts = (const int*)d_in[1];
    float*       out    = (float*)d_out;

    const int vec_per_row = T_LEN / 4;                     // 40000
    const int block = 256;
    dim3 grid((vec_per_row + block - 1) / block, ROWS, 1); // 157 x 256

    RandomShift_33079838113837_kernel<<<grid, block, 0, stream>>>(x, shifts, out);
}